// Round 12
// baseline (6289.380 us; speedup 1.0000x reference)
//
#include <hip/hip_runtime.h>

#define T_ 512
#define N_ 60
#define F_ 2
#define C_ 64
#define H_ 512
#define IN_ 3840
#define FOURH 2048
#define PRED_SZ 61440
#define ADJ_SZ 1843200

// h = 0, c = 0, out frame 0 = feature_input[0] (fp32 copy)
__global__ void init_k(float* h, float* c, const float* feat, float* out)
{
    int i = blockIdx.x * 256 + threadIdx.x;   // grid = 1024 blocks -> 262144
    h[i] = 0.0f;
    c[i] = 0.0f;
    if (i < PRED_SZ) out[i] = feat[i];
}

// GCN from input frames. one block (256 thr) per trajectory t.
// g[t, i*64+c] = norm[i] * sum_j (adj[i][j]+I) * norm[j] * (x[j]@W)[c] + b[c]
__global__ void gcn_bf_k(const float* x, const float* adj,
                         const float* W, const float* b,
                         float* g)
{
    __shared__ float sA[N_][N_];
    __shared__ float sh[N_][C_];
    __shared__ float snorm[N_];
    __shared__ float sW0[C_];
    __shared__ float sW1[C_];
    __shared__ float sb[C_];

    int t = blockIdx.x;
    int tid = threadIdx.x;

    if (tid < C_) {
        sW0[tid] = W[tid];
        sW1[tid] = W[C_ + tid];
        sb[tid] = b[tid];
    }
    for (int l = tid; l < N_ * N_; l += 256) {
        int i = l / N_;
        int j = l - i * N_;
        float a = adj[(long)t * N_ * N_ + l];
        if (i == j) a += 1.0f;
        sA[i][j] = a;
    }
    __syncthreads();

    for (int l = tid; l < N_ * C_; l += 256) {
        int n = l >> 6;
        int cc = l & 63;
        float x0 = x[((long)t * N_ + n) * F_ + 0];
        float x1 = x[((long)t * N_ + n) * F_ + 1];
        sh[n][cc] = x0 * sW0[cc] + x1 * sW1[cc];
    }
    if (tid < N_) {
        float d = 0.0f;
        for (int j = 0; j < N_; ++j) d += sA[tid][j];
        snorm[tid] = (d > 0.0f) ? rsqrtf(d) : 0.0f;
    }
    __syncthreads();

    for (int l = tid; l < N_ * C_; l += 256) {
        int n = l >> 6;
        sh[n][l & 63] *= snorm[n];
    }
    __syncthreads();

    for (int l = tid; l < N_ * C_; l += 256) {
        int i = l >> 6;
        int cc = l & 63;
        float s = 0.0f;
        for (int j = 0; j < N_; ++j) s += sA[i][j] * sh[j][cc];
        g[(long)t * IN_ + l] = snorm[i] * s + sb[cc];
    }
}

// GCN from fp32 workspace (decoder steps 1,2)
__global__ void gcn_ws_k(const float* x, const float* adj,
                         const float* W, const float* b,
                         float* g)
{
    __shared__ float sA[N_][N_];
    __shared__ float sh[N_][C_];
    __shared__ float snorm[N_];
    __shared__ float sW0[C_];
    __shared__ float sW1[C_];
    __shared__ float sb[C_];

    int t = blockIdx.x;
    int tid = threadIdx.x;

    if (tid < C_) {
        sW0[tid] = W[tid];
        sW1[tid] = W[C_ + tid];
        sb[tid] = b[tid];
    }
    for (int l = tid; l < N_ * N_; l += 256) {
        int i = l / N_;
        int j = l - i * N_;
        float a = adj[(long)t * N_ * N_ + l];
        if (i == j) a += 1.0f;
        sA[i][j] = a;
    }
    __syncthreads();

    for (int l = tid; l < N_ * C_; l += 256) {
        int n = l >> 6;
        int cc = l & 63;
        float x0 = x[((long)t * N_ + n) * F_ + 0];
        float x1 = x[((long)t * N_ + n) * F_ + 1];
        sh[n][cc] = x0 * sW0[cc] + x1 * sW1[cc];
    }
    if (tid < N_) {
        float d = 0.0f;
        for (int j = 0; j < N_; ++j) d += sA[tid][j];
        snorm[tid] = (d > 0.0f) ? rsqrtf(d) : 0.0f;
    }
    __syncthreads();

    for (int l = tid; l < N_ * C_; l += 256) {
        int n = l >> 6;
        sh[n][l & 63] *= snorm[n];
    }
    __syncthreads();

    for (int l = tid; l < N_ * C_; l += 256) {
        int i = l >> 6;
        int cc = l & 63;
        float s = 0.0f;
        for (int j = 0; j < N_; ++j) s += sA[i][j] * sh[j][cc];
        g[(long)t * IN_ + l] = snorm[i] * s + sb[cc];
    }
}

// C[M,Nc] = A[M,K](fp32) @ B^T, B fp32 [Nc,K] row-major.
// acc=0: C = result + bias1 + bias2. acc=1: C += result.
__global__ void gemm_bt_k(const float* A, const float* B,
                          const float* bias1, const float* bias2,
                          float* C, int M, int Nc, int K, int acc)
{
    __shared__ float As[16][64];
    __shared__ float Bs[16][64];
    int tid = threadIdx.x;
    int tx = tid & 15;
    int ty = tid >> 4;
    int row0 = blockIdx.y * 64;
    int col0 = blockIdx.x * 64;
    float accv[4][4];
    for (int r = 0; r < 4; ++r)
        for (int s = 0; s < 4; ++s) accv[r][s] = 0.0f;

    for (int k0 = 0; k0 < K; k0 += 16) {
        for (int i = 0; i < 4; ++i) {
            int l = tid * 4 + i;
            int m = l >> 4;
            int kk = l & 15;
            int gm = row0 + m;
            int gk = k0 + kk;
            As[kk][m] = (gm < M && gk < K) ? A[(long)gm * K + gk] : 0.0f;
        }
        for (int i = 0; i < 4; ++i) {
            int l = tid * 4 + i;
            int n = l >> 4;
            int kk = l & 15;
            int gn = col0 + n;
            int gk = k0 + kk;
            Bs[kk][n] = (gn < Nc && gk < K) ? B[(long)gn * K + gk] : 0.0f;
        }
        __syncthreads();
        for (int kk = 0; kk < 16; ++kk) {
            float a0 = As[kk][ty * 4 + 0];
            float a1 = As[kk][ty * 4 + 1];
            float a2 = As[kk][ty * 4 + 2];
            float a3 = As[kk][ty * 4 + 3];
            float b0 = Bs[kk][tx * 4 + 0];
            float b1 = Bs[kk][tx * 4 + 1];
            float b2 = Bs[kk][tx * 4 + 2];
            float b3 = Bs[kk][tx * 4 + 3];
            accv[0][0] += a0 * b0; accv[0][1] += a0 * b1; accv[0][2] += a0 * b2; accv[0][3] += a0 * b3;
            accv[1][0] += a1 * b0; accv[1][1] += a1 * b1; accv[1][2] += a1 * b2; accv[1][3] += a1 * b3;
            accv[2][0] += a2 * b0; accv[2][1] += a2 * b1; accv[2][2] += a2 * b2; accv[2][3] += a2 * b3;
            accv[3][0] += a3 * b0; accv[3][1] += a3 * b1; accv[3][2] += a3 * b2; accv[3][3] += a3 * b3;
        }
        __syncthreads();
    }

    for (int r = 0; r < 4; ++r) {
        int gm = row0 + ty * 4 + r;
        if (gm >= M) continue;
        for (int s = 0; s < 4; ++s) {
            int gn = col0 + tx * 4 + s;
            if (gn >= Nc) continue;
            float v = accv[r][s];
            if (acc) {
                C[(long)gm * Nc + gn] += v;
            } else {
                v += bias1[gn] + bias2[gn];
                C[(long)gm * Nc + gn] = v;
            }
        }
    }
}

// C[M,Nc] = A[M,K](fp32) @ B + bias, B fp32 [K,Nc] row-major, optional relu.
__global__ void gemm_nt_k(const float* A, const float* B,
                          const float* bias, float* C,
                          int M, int Nc, int K, int relu)
{
    __shared__ float As[16][64];
    __shared__ float Bs[16][64];
    int tid = threadIdx.x;
    int tx = tid & 15;
    int ty = tid >> 4;
    int row0 = blockIdx.y * 64;
    int col0 = blockIdx.x * 64;
    float accv[4][4];
    for (int r = 0; r < 4; ++r)
        for (int s = 0; s < 4; ++s) accv[r][s] = 0.0f;

    for (int k0 = 0; k0 < K; k0 += 16) {
        for (int i = 0; i < 4; ++i) {
            int l = tid * 4 + i;
            int m = l >> 4;
            int kk = l & 15;
            int gm = row0 + m;
            int gk = k0 + kk;
            As[kk][m] = (gm < M && gk < K) ? A[(long)gm * K + gk] : 0.0f;
        }
        for (int i = 0; i < 4; ++i) {
            int l = tid + 256 * i;
            int kk = l >> 6;
            int n = l & 63;
            int gn = col0 + n;
            int gk = k0 + kk;
            Bs[kk][n] = (gn < Nc && gk < K) ? B[(long)gk * Nc + gn] : 0.0f;
        }
        __syncthreads();
        for (int kk = 0; kk < 16; ++kk) {
            float a0 = As[kk][ty * 4 + 0];
            float a1 = As[kk][ty * 4 + 1];
            float a2 = As[kk][ty * 4 + 2];
            float a3 = As[kk][ty * 4 + 3];
            float b0 = Bs[kk][tx * 4 + 0];
            float b1 = Bs[kk][tx * 4 + 1];
            float b2 = Bs[kk][tx * 4 + 2];
            float b3 = Bs[kk][tx * 4 + 3];
            accv[0][0] += a0 * b0; accv[0][1] += a0 * b1; accv[0][2] += a0 * b2; accv[0][3] += a0 * b3;
            accv[1][0] += a1 * b0; accv[1][1] += a1 * b1; accv[1][2] += a1 * b2; accv[1][3] += a1 * b3;
            accv[2][0] += a2 * b0; accv[2][1] += a2 * b1; accv[2][2] += a2 * b2; accv[2][3] += a2 * b3;
            accv[3][0] += a3 * b0; accv[3][1] += a3 * b1; accv[3][2] += a3 * b2; accv[3][3] += a3 * b3;
        }
        __syncthreads();
    }

    for (int r = 0; r < 4; ++r) {
        int gm = row0 + ty * 4 + r;
        if (gm >= M) continue;
        for (int s = 0; s < 4; ++s) {
            int gn = col0 + tx * 4 + s;
            if (gn >= Nc) continue;
            float v = accv[r][s] + bias[gn];
            if (relu && v < 0.0f) v = 0.0f;
            C[(long)gm * Nc + gn] = v;
        }
    }
}

// gates [T,4H] order (i,f,g,o)
__global__ void lstm_k(const float* gates, float* h, float* c)
{
    int idx = blockIdx.x * 256 + threadIdx.x;   // 1024 blocks -> 262144
    int t = idx >> 9;
    int j = idx & 511;
    const float* gr = gates + (long)t * FOURH;
    float ig = 1.0f / (1.0f + expf(-gr[j]));
    float fg = 1.0f / (1.0f + expf(-gr[512 + j]));
    float gg = tanhf(gr[1024 + j]);
    float og = 1.0f / (1.0f + expf(-gr[1536 + j]));
    float cn = fg * c[idx] + ig * gg;
    c[idx] = cn;
    h[idx] = og * tanhf(cn);
}

// store fp32 pred into fp32 output frame
__global__ void store_k(const float* pred, float* dst)
{
    int i = blockIdx.x * 256 + threadIdx.x;   // 240 blocks -> 61440
    dst[i] = pred[i];
}

__global__ void adj_k(const float* pred, const float* stdv,
                      const float* meanv, float* adj)
{
    __shared__ float sx0[N_];
    __shared__ float sx1[N_];
    __shared__ int sex[N_];
    int t = blockIdx.x;
    int tid = threadIdx.x;
    if (tid < N_) {
        float a = pred[(long)t * 120 + tid * 2 + 0] * stdv[0] + meanv[0];
        float b = pred[(long)t * 120 + tid * 2 + 1] * stdv[1] + meanv[1];
        sx0[tid] = a;
        sx1[tid] = b;
        sex[tid] = (a > 0.04f) && (b > 0.04f);
    }
    __syncthreads();
    for (int l = tid; l < N_ * N_; l += 256) {
        int i = l / N_;
        int j = l - i * N_;
        float dx = sx0[i] - sx0[j];
        float dy = sx1[i] - sx1[j];
        float d = sqrtf(dx * dx + dy * dy);
        int conn = ((d > 0.0f) && (d < 10.0f)) || (i == j);
        adj[(long)t * (N_ * N_) + l] = (sex[i] && sex[j] && conn) ? 1.0f : 0.0f;
    }
}

extern "C" void kernel_launch(void* const* d_in, const int* in_sizes, int n_in,
                              void* d_out, int out_size, void* d_ws, size_t ws_size,
                              hipStream_t stream)
{
    const float* feat  = (const float*)d_in[0];
    const float* adjin = (const float*)d_in[1];
    const float* stdv  = (const float*)d_in[2];
    const float* meanv = (const float*)d_in[3];
    const float* gcnW  = (const float*)d_in[4];
    const float* gcnb  = (const float*)d_in[5];
    const float* Wih   = (const float*)d_in[6];
    const float* Whh   = (const float*)d_in[7];
    const float* bih   = (const float*)d_in[8];
    const float* bhh   = (const float*)d_in[9];
    const float* W1    = (const float*)d_in[10];
    const float* b1    = (const float*)d_in[11];
    const float* W2    = (const float*)d_in[12];
    const float* b2    = (const float*)d_in[13];
    const float* W3    = (const float*)d_in[14];
    const float* b3    = (const float*)d_in[15];
    const float* W4    = (const float*)d_in[16];
    const float* b4    = (const float*)d_in[17];
    float* out = (float*)d_out;

    float* g     = (float*)d_ws;            // 512*3840
    float* gates = g + 1966080;             // 512*2048
    float* h     = gates + 1048576;         // 512*512
    float* c     = h + 262144;              // 512*512
    float* m1    = c + 262144;              // 512*512
    float* m2    = m1 + 262144;             // 512*1028
    float* m3    = m2 + 526336;             // 512*512
    float* pred  = m3 + 262144;             // 512*120
    float* adjws = pred + 61440;            // 512*3600

    init_k<<<1024, 256, 0, stream>>>(h, c, feat, out);

    for (int step = 0; step < 7; ++step) {
        if (step < 5)
            gcn_bf_k<<<T_, 256, 0, stream>>>(feat + (long)step * PRED_SZ,
                                             adjin + (long)step * ADJ_SZ,
                                             gcnW, gcnb, g);
        else
            gcn_ws_k<<<T_, 256, 0, stream>>>(pred, adjws, gcnW, gcnb, g);

        gemm_bt_k<<<dim3(32, 8), 256, 0, stream>>>(g, Wih, bih, bhh, gates, T_, FOURH, IN_, 0);
        gemm_bt_k<<<dim3(32, 8), 256, 0, stream>>>(h, Whh, bih, bhh, gates, T_, FOURH, H_, 1);
        lstm_k<<<1024, 256, 0, stream>>>(gates, h, c);
        gemm_nt_k<<<dim3(8, 8), 256, 0, stream>>>(h, W1, b1, m1, T_, 512, 512, 1);
        gemm_nt_k<<<dim3(17, 8), 256, 0, stream>>>(m1, W2, b2, m2, T_, 1028, 512, 1);
        gemm_nt_k<<<dim3(8, 8), 256, 0, stream>>>(m2, W3, b3, m3, T_, 512, 1028, 1);
        gemm_nt_k<<<dim3(2, 8), 256, 0, stream>>>(m3, W4, b4, pred, T_, 120, 512, 0);
        store_k<<<240, 256, 0, stream>>>(pred, out + (long)(step + 1) * PRED_SZ);
        if (step == 4 || step == 5)
            adj_k<<<T_, 256, 0, stream>>>(pred, stdv, meanv, adjws);
    }
}

// Round 13
// 1721.174 us; speedup vs baseline: 3.6541x; 3.6541x over previous
//
#include <hip/hip_runtime.h>

#define T_ 512
#define N_ 60
#define F_ 2
#define C_ 64
#define H_ 512
#define IN_ 3840
#define FOURH 2048
#define PRED_SZ 61440
#define ADJ_SZ 1843200
#define LDSK 40   // padded LDS row stride in bf16 units (2-way conflicts only)

typedef __attribute__((ext_vector_type(8))) short bf8;
typedef __attribute__((ext_vector_type(4))) float f4;

__device__ __forceinline__ unsigned short f2bf(float f)
{
    unsigned int u = __float_as_uint(f);
    u = (u + 0x7FFFu + ((u >> 16) & 1u)) >> 16;
    return (unsigned short)u;
}

// cast fp32 -> bf16 (weights, once per launch)
__global__ void cast_k(const float* src, unsigned short* dst, int n)
{
    int i = blockIdx.x * 256 + threadIdx.x;
    if (i < n) dst[i] = f2bf(src[i]);
}

// h_bf = 0, c = 0, out frame 0 = feature_input[0]
__global__ void init_k(unsigned short* h_bf, float* c, const float* feat, float* out)
{
    int i = blockIdx.x * 256 + threadIdx.x;   // 1024 blocks -> 262144
    h_bf[i] = 0;
    c[i] = 0.0f;
    if (i < PRED_SZ) out[i] = feat[i];
}

// Encoder GCN (input frames) -> g_bf (bf16)
__global__ void gcn_enc_k(const float* x, const float* adj,
                          const float* W, const float* b, unsigned short* g_bf)
{
    __shared__ float sA[N_][N_];
    __shared__ float sh[N_][C_];
    __shared__ float snorm[N_];
    __shared__ float sW0[C_];
    __shared__ float sW1[C_];
    __shared__ float sb[C_];

    int t = blockIdx.x;
    int tid = threadIdx.x;

    if (tid < C_) {
        sW0[tid] = W[tid];
        sW1[tid] = W[C_ + tid];
        sb[tid] = b[tid];
    }
    for (int l = tid; l < N_ * N_; l += 256) {
        int i = l / N_;
        int j = l - i * N_;
        float a = adj[(long)t * N_ * N_ + l];
        if (i == j) a += 1.0f;
        sA[i][j] = a;
    }
    __syncthreads();

    for (int l = tid; l < N_ * C_; l += 256) {
        int n = l >> 6;
        int cc = l & 63;
        float x0 = x[((long)t * N_ + n) * F_ + 0];
        float x1 = x[((long)t * N_ + n) * F_ + 1];
        sh[n][cc] = x0 * sW0[cc] + x1 * sW1[cc];
    }
    if (tid < N_) {
        float d = 0.0f;
        for (int j = 0; j < N_; ++j) d += sA[tid][j];
        snorm[tid] = (d > 0.0f) ? rsqrtf(d) : 0.0f;
    }
    __syncthreads();

    for (int l = tid; l < N_ * C_; l += 256) {
        int n = l >> 6;
        sh[n][l & 63] *= snorm[n];
    }
    __syncthreads();

    for (int l = tid; l < N_ * C_; l += 256) {
        int i = l >> 6;
        int cc = l & 63;
        float s = 0.0f;
        for (int j = 0; j < N_; ++j) s += sA[i][j] * sh[j][cc];
        g_bf[(long)t * IN_ + l] = f2bf(snorm[i] * s + sb[cc]);
    }
}

// Decoder GCN: radius-graph built in-kernel from pred (replaces adj_k + gcn_ws_k)
__global__ void gcn_dec_k(const float* pred, const float* stdv, const float* meanv,
                          const float* W, const float* b, unsigned short* g_bf)
{
    __shared__ float sA[N_][N_];
    __shared__ float sh[N_][C_];
    __shared__ float snorm[N_];
    __shared__ float sW0[C_];
    __shared__ float sW1[C_];
    __shared__ float sb[C_];
    __shared__ float sx0[N_];
    __shared__ float sx1[N_];
    __shared__ int sex[N_];

    int t = blockIdx.x;
    int tid = threadIdx.x;

    if (tid < C_) {
        sW0[tid] = W[tid];
        sW1[tid] = W[C_ + tid];
        sb[tid] = b[tid];
    }
    if (tid < N_) {
        float dx = pred[(long)t * 120 + tid * 2 + 0] * stdv[0] + meanv[0];
        float dy = pred[(long)t * 120 + tid * 2 + 1] * stdv[1] + meanv[1];
        sx0[tid] = dx;
        sx1[tid] = dy;
        sex[tid] = (dx > 0.04f) && (dy > 0.04f);
    }
    __syncthreads();

    for (int l = tid; l < N_ * N_; l += 256) {
        int i = l / N_;
        int j = l - i * N_;
        float dx = sx0[i] - sx0[j];
        float dy = sx1[i] - sx1[j];
        float d = sqrtf(dx * dx + dy * dy);
        int conn = ((d > 0.0f) && (d < 10.0f)) || (i == j);
        float a = (sex[i] && sex[j] && conn) ? 1.0f : 0.0f;
        if (i == j) a += 1.0f;     // GCN self-loop on top of radius graph
        sA[i][j] = a;
    }
    __syncthreads();

    for (int l = tid; l < N_ * C_; l += 256) {
        int n = l >> 6;
        int cc = l & 63;
        float x0 = pred[(long)t * 120 + n * 2 + 0];
        float x1 = pred[(long)t * 120 + n * 2 + 1];
        sh[n][cc] = x0 * sW0[cc] + x1 * sW1[cc];
    }
    if (tid < N_) {
        float d = 0.0f;
        for (int j = 0; j < N_; ++j) d += sA[tid][j];
        snorm[tid] = (d > 0.0f) ? rsqrtf(d) : 0.0f;
    }
    __syncthreads();

    for (int l = tid; l < N_ * C_; l += 256) {
        int n = l >> 6;
        sh[n][l & 63] *= snorm[n];
    }
    __syncthreads();

    for (int l = tid; l < N_ * C_; l += 256) {
        int i = l >> 6;
        int cc = l & 63;
        float s = 0.0f;
        for (int j = 0; j < N_; ++j) s += sA[i][j] * sh[j][cc];
        g_bf[(long)t * IN_ + l] = f2bf(snorm[i] * s + sb[cc]);
    }
}

// ---------------------------------------------------------------------------
// MFMA GEMM: C[M,Nc] = A(bf16)[M,K] @ B (+bias), fp32 accumulate.
// BT=1: B stored [Nc][K]; BT=0: B stored [K][Nc].
// BBF=1: B is bf16; BBF=0: B is fp32 (cast during staging).
// mode 0: Cf = acc + bias1 + bias2      (gates init)
// mode 1: Cf += acc                     (gates accumulate)
// mode 2: Cbf = bf16(relu(acc + bias1)) (MLP hidden)
// mode 3: Cf = acc + bias1              (pred)
// 64x64 tile, BK=32, 256 threads = 4 waves, each wave 32x32 via 2x2 mfma 16x16x32.
// ---------------------------------------------------------------------------
__global__ __launch_bounds__(256) void mgemm(
    const unsigned short* Abf, const void* Bp,
    const float* bias1, const float* bias2,
    float* Cf, unsigned short* Cbf,
    int M, int Nc, int K, int BT, int BBF, int mode)
{
    __shared__ unsigned short As[64 * LDSK];
    __shared__ unsigned short Bs[64 * LDSK];

    int tid = threadIdx.x;
    int wave = tid >> 6;
    int lane = tid & 63;
    int quad = lane >> 4;
    int l16 = lane & 15;
    int wr = (wave >> 1) * 32;
    int wc = (wave & 1) * 32;
    int row0 = blockIdx.y * 64;
    int col0 = blockIdx.x * 64;

    f4 acc00 = {0.f, 0.f, 0.f, 0.f};
    f4 acc01 = {0.f, 0.f, 0.f, 0.f};
    f4 acc10 = {0.f, 0.f, 0.f, 0.f};
    f4 acc11 = {0.f, 0.f, 0.f, 0.f};

    const ushort4 zu = make_ushort4(0, 0, 0, 0);

    for (int k0 = 0; k0 < K; k0 += 32) {
        // --- stage A tile: 64 rows x 32 k (bf16) ---
        {
            int r = tid >> 2;
            int ko = (tid & 3) * 8;
            int gm = row0 + r;
            int gk = k0 + ko;
            ushort4 v0 = zu, v1 = zu;
            if (gm < M) {
                if (gk + 4 <= K) v0 = *(const ushort4*)&Abf[(long)gm * K + gk];
                if (gk + 8 <= K) v1 = *(const ushort4*)&Abf[(long)gm * K + gk + 4];
            }
            *(ushort4*)&As[r * LDSK + ko]     = v0;
            *(ushort4*)&As[r * LDSK + ko + 4] = v1;
        }
        // --- stage B tile into Bs[n][k] ---
        if (BT) {
            int n = tid >> 2;
            int ko = (tid & 3) * 8;
            int gn = col0 + n;
            int gk = k0 + ko;
            ushort4 v0 = zu, v1 = zu;
            if (gn < Nc) {
                if (BBF) {
                    const unsigned short* Bb = (const unsigned short*)Bp;
                    if (gk + 4 <= K) v0 = *(const ushort4*)&Bb[(long)gn * K + gk];
                    if (gk + 8 <= K) v1 = *(const ushort4*)&Bb[(long)gn * K + gk + 4];
                } else {
                    const float* Bf = (const float*)Bp;
                    if (gk + 4 <= K) {
                        float4 f = *(const float4*)&Bf[(long)gn * K + gk];
                        v0 = make_ushort4(f2bf(f.x), f2bf(f.y), f2bf(f.z), f2bf(f.w));
                    }
                    if (gk + 8 <= K) {
                        float4 f = *(const float4*)&Bf[(long)gn * K + gk + 4];
                        v1 = make_ushort4(f2bf(f.x), f2bf(f.y), f2bf(f.z), f2bf(f.w));
                    }
                }
            }
            *(ushort4*)&Bs[n * LDSK + ko]     = v0;
            *(ushort4*)&Bs[n * LDSK + ko + 4] = v1;
        } else {
            int kk = tid >> 3;
            int np = (tid & 7) * 8;
            int gk = k0 + kk;
            int gn0 = col0 + np;
            unsigned short vals[8];
            for (int i = 0; i < 8; ++i) vals[i] = 0;
            if (gk < K) {
                if (BBF) {
                    const unsigned short* Bb = (const unsigned short*)Bp;
                    if (gn0 + 4 <= Nc) {
                        ushort4 u = *(const ushort4*)&Bb[(long)gk * Nc + gn0];
                        vals[0] = u.x; vals[1] = u.y; vals[2] = u.z; vals[3] = u.w;
                    }
                    if (gn0 + 8 <= Nc) {
                        ushort4 u = *(const ushort4*)&Bb[(long)gk * Nc + gn0 + 4];
                        vals[4] = u.x; vals[5] = u.y; vals[6] = u.z; vals[7] = u.w;
                    }
                } else {
                    const float* Bf = (const float*)Bp;
                    if (gn0 + 4 <= Nc) {
                        float4 f = *(const float4*)&Bf[(long)gk * Nc + gn0];
                        vals[0] = f2bf(f.x); vals[1] = f2bf(f.y); vals[2] = f2bf(f.z); vals[3] = f2bf(f.w);
                    }
                    if (gn0 + 8 <= Nc) {
                        float4 f = *(const float4*)&Bf[(long)gk * Nc + gn0 + 4];
                        vals[4] = f2bf(f.x); vals[5] = f2bf(f.y); vals[6] = f2bf(f.z); vals[7] = f2bf(f.w);
                    }
                }
            }
            for (int i = 0; i < 8; ++i) Bs[(np + i) * LDSK + kk] = vals[i];
        }
        __syncthreads();

        // --- fragments + 4 MFMAs ---
        bf8 a0 = *(const bf8*)&As[(wr + l16) * LDSK + quad * 8];
        bf8 a1 = *(const bf8*)&As[(wr + 16 + l16) * LDSK + quad * 8];
        bf8 b0 = *(const bf8*)&Bs[(wc + l16) * LDSK + quad * 8];
        bf8 b1 = *(const bf8*)&Bs[(wc + 16 + l16) * LDSK + quad * 8];

        acc00 = __builtin_amdgcn_mfma_f32_16x16x32_bf16(a0, b0, acc00, 0, 0, 0);
        acc01 = __builtin_amdgcn_mfma_f32_16x16x32_bf16(a0, b1, acc01, 0, 0, 0);
        acc10 = __builtin_amdgcn_mfma_f32_16x16x32_bf16(a1, b0, acc10, 0, 0, 0);
        acc11 = __builtin_amdgcn_mfma_f32_16x16x32_bf16(a1, b1, acc11, 0, 0, 0);
        __syncthreads();
    }

    // --- epilogue: D[row=quad*4+r][col=l16] per 16x16 tile ---
    for (int mi = 0; mi < 2; ++mi) {
        for (int ni = 0; ni < 2; ++ni) {
            for (int r = 0; r < 4; ++r) {
                int gm = row0 + wr + mi * 16 + quad * 4 + r;
                int gn = col0 + wc + ni * 16 + l16;
                if (gm >= M || gn >= Nc) continue;
                float v;
                if (mi == 0 && ni == 0) v = acc00[r];
                else if (mi == 0)       v = acc01[r];
                else if (ni == 0)       v = acc10[r];
                else                    v = acc11[r];
                long idx = (long)gm * Nc + gn;
                if (mode == 0) {
                    Cf[idx] = v + bias1[gn] + bias2[gn];
                } else if (mode == 1) {
                    Cf[idx] += v;
                } else if (mode == 2) {
                    v += bias1[gn];
                    if (v < 0.0f) v = 0.0f;
                    Cbf[idx] = f2bf(v);
                } else {
                    Cf[idx] = v + bias1[gn];
                }
            }
        }
    }
}

// gates [T,4H] order (i,f,g,o) -> h_bf (bf16), c (fp32)
__global__ void lstm_k(const float* gates, unsigned short* h_bf, float* c)
{
    int idx = blockIdx.x * 256 + threadIdx.x;   // 1024 blocks -> 262144
    int t = idx >> 9;
    int j = idx & 511;
    const float* gr = gates + (long)t * FOURH;
    float ig = 1.0f / (1.0f + expf(-gr[j]));
    float fg = 1.0f / (1.0f + expf(-gr[512 + j]));
    float gg = tanhf(gr[1024 + j]);
    float og = 1.0f / (1.0f + expf(-gr[1536 + j]));
    float cn = fg * c[idx] + ig * gg;
    c[idx] = cn;
    h_bf[idx] = f2bf(og * tanhf(cn));
}

__global__ void store_k(const float* pred, float* dst)
{
    int i = blockIdx.x * 256 + threadIdx.x;   // 240 blocks -> 61440
    dst[i] = pred[i];
}

extern "C" void kernel_launch(void* const* d_in, const int* in_sizes, int n_in,
                              void* d_out, int out_size, void* d_ws, size_t ws_size,
                              hipStream_t stream)
{
    const float* feat  = (const float*)d_in[0];
    const float* adjin = (const float*)d_in[1];
    const float* stdv  = (const float*)d_in[2];
    const float* meanv = (const float*)d_in[3];
    const float* gcnW  = (const float*)d_in[4];
    const float* gcnb  = (const float*)d_in[5];
    const float* Wih   = (const float*)d_in[6];
    const float* Whh   = (const float*)d_in[7];
    const float* bih   = (const float*)d_in[8];
    const float* bhh   = (const float*)d_in[9];
    const float* W1    = (const float*)d_in[10];
    const float* b1    = (const float*)d_in[11];
    const float* W2    = (const float*)d_in[12];
    const float* b2    = (const float*)d_in[13];
    const float* W3    = (const float*)d_in[14];
    const float* b3    = (const float*)d_in[15];
    const float* W4    = (const float*)d_in[16];
    const float* b4    = (const float*)d_in[17];
    float* out = (float*)d_out;

    // fp32 scratch
    float* gates = (float*)d_ws;                // 1,048,576 f
    float* c     = gates + 1048576;             //   262,144 f
    float* pred  = c + 262144;                  //    61,440 f
    // bf16 scratch
    unsigned short* g_bf   = (unsigned short*)(pred + 61440);  // 1,966,080
    unsigned short* h_bf   = g_bf + 1966080;    //   262,144
    unsigned short* m1_bf  = h_bf + 262144;     //   262,144
    unsigned short* m2_bf  = m1_bf + 262144;    //   526,336
    unsigned short* m3_bf  = m2_bf + 526336;    //   262,144
    unsigned short* Whh_bf = m3_bf + 262144;    // 1,048,576
    unsigned short* W1_bf  = Whh_bf + 1048576;  //   262,144
    unsigned short* W2_bf  = W1_bf + 262144;    //   526,336
    unsigned short* W3_bf  = W2_bf + 526336;    //   526,336
    unsigned short* W4_bf  = W3_bf + 526336;    //    61,440
    unsigned short* Wih_bf = W4_bf + 61440;     // 7,864,320 (only if ws allows)
    // base usage ~16.9 MB (proven ws >= ~25 MB); W_ih precast needs ~32.7 MB total
    int pre_ih = (ws_size >= (size_t)34u * 1024u * 1024u) ? 1 : 0;

    // weight casts (once per launch; graph-safe: same work every call)
    cast_k<<<(1048576 + 255) / 256, 256, 0, stream>>>(Whh, Whh_bf, 1048576);
    cast_k<<<(262144 + 255) / 256, 256, 0, stream>>>(W1, W1_bf, 262144);
    cast_k<<<(526336 + 255) / 256, 256, 0, stream>>>(W2, W2_bf, 526336);
    cast_k<<<(526336 + 255) / 256, 256, 0, stream>>>(W3, W3_bf, 526336);
    cast_k<<<(61440 + 255) / 256, 256, 0, stream>>>(W4, W4_bf, 61440);
    if (pre_ih)
        cast_k<<<(7864320 + 255) / 256, 256, 0, stream>>>(Wih, Wih_bf, 7864320);

    init_k<<<1024, 256, 0, stream>>>(h_bf, c, feat, out);

    for (int step = 0; step < 7; ++step) {
        if (step < 5)
            gcn_enc_k<<<T_, 256, 0, stream>>>(feat + (long)step * PRED_SZ,
                                              adjin + (long)step * ADJ_SZ,
                                              gcnW, gcnb, g_bf);
        else
            gcn_dec_k<<<T_, 256, 0, stream>>>(pred, stdv, meanv, gcnW, gcnb, g_bf);

        // gates = g @ Wih^T + bih + bhh ; gates += h @ Whh^T
        if (pre_ih)
            mgemm<<<dim3(32, 8), 256, 0, stream>>>(g_bf, Wih_bf, bih, bhh, gates, (unsigned short*)0,
                                                   T_, FOURH, IN_, 1, 1, 0);
        else
            mgemm<<<dim3(32, 8), 256, 0, stream>>>(g_bf, Wih, bih, bhh, gates, (unsigned short*)0,
                                                   T_, FOURH, IN_, 1, 0, 0);
        mgemm<<<dim3(32, 8), 256, 0, stream>>>(h_bf, Whh_bf, (const float*)0, (const float*)0,
                                               gates, (unsigned short*)0, T_, FOURH, H_, 1, 1, 1);
        lstm_k<<<1024, 256, 0, stream>>>(gates, h_bf, c);

        // MLP: h -> 512 -> 1028 -> 512 -> 120
        mgemm<<<dim3(8, 8), 256, 0, stream>>>(h_bf, W1_bf, b1, (const float*)0,
                                              (float*)0, m1_bf, T_, 512, 512, 0, 1, 2);
        mgemm<<<dim3(17, 8), 256, 0, stream>>>(m1_bf, W2_bf, b2, (const float*)0,
                                               (float*)0, m2_bf, T_, 1028, 512, 0, 1, 2);
        mgemm<<<dim3(8, 8), 256, 0, stream>>>(m2_bf, W3_bf, b3, (const float*)0,
                                              (float*)0, m3_bf, T_, 512, 1028, 0, 1, 2);
        mgemm<<<dim3(2, 8), 256, 0, stream>>>(m3_bf, W4_bf, b4, (const float*)0,
                                              pred, (unsigned short*)0, T_, 120, 512, 0, 1, 3);

        store_k<<<240, 256, 0, stream>>>(pred, out + (long)(step + 1) * PRED_SZ);
    }
}